// Round 1
// baseline (14.202 us; speedup 1.0000x reference)
//
#include <hip/hip_runtime.h>

// Morph2D: reference = extract 3x3 SAME patches, *se, sort over 144, sum.
// sum∘sort == sum  =>  this is exactly a 3x3 conv x[B,H,W,C] * se[3,3,C,F].
// Output flat layout is [B, F, H*W] (the reference's reshape is a raw
// reinterpret of that buffer, not a transpose).

#define Bc 2
#define Hc 192
#define Wc 192
#define Cc 16
#define Fc 8
#define HWc (Hc * Wc)

__global__ __launch_bounds__(256) void morph2d_conv(
    const float* __restrict__ x,    // [B,H,W,C]
    const float* __restrict__ se,   // [3,3,C,F]
    float* __restrict__ out)        // flat [B,F,HW]
{
    __shared__ float s_se[9 * Cc * Fc];  // 1152 floats = 4.5 KiB
    for (int i = threadIdx.x; i < 9 * Cc * Fc; i += blockDim.x)
        s_se[i] = se[i];
    __syncthreads();

    int gid = blockIdx.x * blockDim.x + threadIdx.x;  // over B*H*W
    if (gid >= Bc * HWc) return;
    int b  = gid / HWc;
    int hw = gid - b * HWc;
    int h  = hw / Wc;
    int w  = hw - h * Wc;

    float acc[Fc] = {0.f, 0.f, 0.f, 0.f, 0.f, 0.f, 0.f, 0.f};

    #pragma unroll
    for (int kh = 0; kh < 3; ++kh) {
        int hy = h + kh - 1;
        if (hy < 0 || hy >= Hc) continue;
        #pragma unroll
        for (int kw = 0; kw < 3; ++kw) {
            int wx = w + kw - 1;
            if (wx < 0 || wx >= Wc) continue;
            const float* xp = x + ((long)(b * Hc + hy) * Wc + wx) * Cc;
            const float* sp = s_se + (kh * 3 + kw) * Cc * Fc;
            #pragma unroll
            for (int c4 = 0; c4 < Cc / 4; ++c4) {
                float4 xv = *reinterpret_cast<const float4*>(xp + c4 * 4);
                const float* s0 = sp + (c4 * 4) * Fc;  // wave-uniform -> LDS broadcast
                #pragma unroll
                for (int f = 0; f < Fc; ++f) {
                    acc[f] += xv.x * s0[0 * Fc + f];
                    acc[f] += xv.y * s0[1 * Fc + f];
                    acc[f] += xv.z * s0[2 * Fc + f];
                    acc[f] += xv.w * s0[3 * Fc + f];
                }
            }
        }
    }

    // out flat = [B, F, HW]; consecutive threads (consecutive hw) -> coalesced
    #pragma unroll
    for (int f = 0; f < Fc; ++f)
        out[(b * Fc + f) * HWc + hw] = acc[f];
}

extern "C" void kernel_launch(void* const* d_in, const int* in_sizes, int n_in,
                              void* d_out, int out_size, void* d_ws, size_t ws_size,
                              hipStream_t stream) {
    const float* x  = (const float*)d_in[0];
    const float* se = (const float*)d_in[1];
    // d_in[2] = ranks: unused by the reference's actual output (it sums
    // sorted_list, not mul_2).
    float* out = (float*)d_out;

    int total = Bc * HWc;  // 73728
    int block = 256;
    int grid  = (total + block - 1) / block;  // 288
    morph2d_conv<<<grid, block, 0, stream>>>(x, se, out);
}